// Round 6
// baseline (396.998 us; speedup 1.0000x reference)
//
#include <hip/hip_runtime.h>
#include <hip/hip_bf16.h>

// NNP species-MLP energy sum, v2: NO sort. Natural-order 16-atom tiles
// (500000 = 16*31250 exactly -> no tail masking). Each wave computes all 4
// species' MLPs per tile via bf16 MFMA (W0 B-frags from LDS, W1/biases in
// regs) and selects per-row by species. desc reads are perfectly sequential
// -> true streaming at HBM BW. 2 kernel launches total.

#define NATOMS 500000
#define NSPEC  4
#define DIN    128
#define DH1    32
#define DH2    32
#define NTILES (NATOMS / 16)          // 31250 exact

#define K4_BLOCKS 768
#define K4_WAVES  (K4_BLOCKS * 4)     // 3072
#define CHUNK     ((NTILES + K4_WAVES - 1) / K4_WAVES)   // 11

// ---- ws layout: per-species frag block, stride 11776 B ----
//   W0 frags : 8 frags (kt0..3 x jt0..1) * 64 lanes * 16B  @ 0     (8192B)
//   W1 frags : 2 frags * 64 * 16B                          @ 8192  (2048B)
//   b0 pairs : 2 * 64 * f32                                @ 10240 (512B)
//   b1 pairs : 2 * 64 * f32                                @ 10752 (512B)
//   W2 pairs : 2 * 64 * f32                                @ 11264 (512B)
#define SPEC_STRIDE 11776

typedef __bf16 bf16x8 __attribute__((ext_vector_type(8)));
typedef float  f32x4  __attribute__((ext_vector_type(4)));

__device__ __forceinline__ float fast_tanh(float x) {
    // tanh(x) = 1 - 2/(exp2(x*2/ln2)+1); HW exp2 + HW rcp (~1e-6 rel err,
    // way under the 2% bf16 threshold). Saturates correctly at +/-inf.
    float e = __builtin_amdgcn_exp2f(x * 2.8853900817779268f);
    return 1.0f - 2.0f * __builtin_amdgcn_rcpf(e + 1.0f);
}

// ---------- prep: zero out + build MFMA B-fragments (4sp x 64 lanes) ------
__global__ void kprep(const float* __restrict__ W0, const float* __restrict__ b0,
                      const float* __restrict__ W1, const float* __restrict__ b1,
                      const float* __restrict__ W2, char* ws, float* out) {
    int tid = threadIdx.x;
    if (tid == 0) out[0] = 0.0f;

    int s = tid >> 6, l = tid & 63;
    int kg = l >> 4, lo = l & 15;
    char* fb = ws + (size_t)s * SPEC_STRIDE;

    // W0: B[k][j], k = kt*32 + kg*8 + e, j = jt*16 + lo  (verified layout)
    for (int kt = 0; kt < 4; kt++) {
        for (int jt = 0; jt < 2; jt++) {
            bf16x8 v;
            for (int e = 0; e < 8; e++)
                v[e] = (__bf16)W0[(s * DIN + kt * 32 + kg * 8 + e) * DH1 + jt * 16 + lo];
            *(bf16x8*)(fb + (kt * 2 + jt) * 1024 + l * 16) = v;
        }
    }
    // W1: k = kg*8 + e (K=32 single step)
    for (int jt = 0; jt < 2; jt++) {
        bf16x8 v;
        for (int e = 0; e < 8; e++)
            v[e] = (__bf16)W1[(s * DH1 + kg * 8 + e) * DH2 + jt * 16 + lo];
        *(bf16x8*)(fb + 8192 + jt * 1024 + l * 16) = v;
    }
    for (int jt = 0; jt < 2; jt++) {
        *(float*)(fb + 10240 + (jt * 64 + l) * 4) = b0[s * DH1 + jt * 16 + lo];
        *(float*)(fb + 10752 + (jt * 64 + l) * 4) = b1[s * DH2 + jt * 16 + lo];
        *(float*)(fb + 11264 + (jt * 64 + l) * 4) = W2[s * DH2 + jt * 16 + lo];
    }
}

// ---------- main: stream desc, all-species MFMA, per-row select ----------
__global__ __launch_bounds__(256) void k4_all(const float* __restrict__ desc,
                                              const int* __restrict__ species,
                                              const float* __restrict__ b2g,
                                              const char* __restrict__ ws,
                                              float* __restrict__ out) {
    __shared__ __align__(16) char w0lds[4 * 8192];          // 32KB W0 frags
    __shared__ __align__(16) __bf16 h1buf[4][16][32];       // 4KB relayout

    int tid = threadIdx.x, l = tid & 63, w = tid >> 6;
    int lo = l & 15, kg = l >> 4;

    // stage W0 frags into LDS (linear copy preserves frag addressing)
    for (int s = 0; s < 4; s++) {
#pragma unroll
        for (int i = 0; i < 2; i++) {
            int off = (i * 256 + tid) * 16;
            *(float4*)(w0lds + s * 8192 + off) =
                *(const float4*)(ws + (size_t)s * SPEC_STRIDE + off);
        }
    }
    __syncthreads();

    // per-lane weight registers (all statically indexed via unrolled loops)
    bf16x8 w1f[4][2];
    float  b0f[4][2], b1f[4][2], w2f[4][2], b2v[4];
#pragma unroll
    for (int s = 0; s < 4; s++) {
        const char* fb = ws + (size_t)s * SPEC_STRIDE;
        w1f[s][0] = *(const bf16x8*)(fb + 8192 + l * 16);
        w1f[s][1] = *(const bf16x8*)(fb + 8192 + 1024 + l * 16);
        b0f[s][0] = *(const float*)(fb + 10240 + l * 4);
        b0f[s][1] = *(const float*)(fb + 10240 + (64 + l) * 4);
        b1f[s][0] = *(const float*)(fb + 10752 + l * 4);
        b1f[s][1] = *(const float*)(fb + 10752 + (64 + l) * 4);
        w2f[s][0] = *(const float*)(fb + 11264 + l * 4);
        w2f[s][1] = *(const float*)(fb + 11264 + (64 + l) * 4);
        b2v[s]    = b2g[s];
    }

    int gw = blockIdx.x * 4 + w;
    int t0 = gw * CHUNK;
    int t1 = t0 + CHUNK; if (t1 > NTILES) t1 = NTILES;
    float esum = 0.0f;

#define LOAD8(T_) do {                                                        \
    const float* dp_ = desc + ((size_t)(T_) * 16 + lo) * DIN + kg * 8;        \
    dA[0] = *(const float4*)(dp_);       dA[1] = *(const float4*)(dp_ + 4);   \
    dA[2] = *(const float4*)(dp_ + 32);  dA[3] = *(const float4*)(dp_ + 36);  \
    dA[4] = *(const float4*)(dp_ + 64);  dA[5] = *(const float4*)(dp_ + 68);  \
    dA[6] = *(const float4*)(dp_ + 96);  dA[7] = *(const float4*)(dp_ + 100); \
} while (0)

    if (t0 < t1) {
        float4 dA[8];
        LOAD8(t0);
        for (int t = t0; t < t1; ++t) {
            // convert current tile to bf16 A-frags, freeing dA for prefetch
            bf16x8 a[4];
#pragma unroll
            for (int kt = 0; kt < 4; kt++) {
                float4 x = dA[2 * kt], y = dA[2 * kt + 1];
                bf16x8 aa;
                aa[0] = (__bf16)x.x; aa[1] = (__bf16)x.y;
                aa[2] = (__bf16)x.z; aa[3] = (__bf16)x.w;
                aa[4] = (__bf16)y.x; aa[5] = (__bf16)y.y;
                aa[6] = (__bf16)y.z; aa[7] = (__bf16)y.w;
                a[kt] = aa;
            }
            if (t + 1 < t1) LOAD8(t + 1);   // prefetch next tile under compute

            int p0 = t * 16;
            int sv = species[p0 + lo];
            int spr0 = __shfl(sv, kg * 4 + 0);
            int spr1 = __shfl(sv, kg * 4 + 1);
            int spr2 = __shfl(sv, kg * 4 + 2);
            int spr3 = __shfl(sv, kg * 4 + 3);

#pragma unroll
            for (int sp = 0; sp < 4; sp++) {
                f32x4 acc0 = {0.f, 0.f, 0.f, 0.f}, acc1 = {0.f, 0.f, 0.f, 0.f};
#pragma unroll
                for (int kt = 0; kt < 4; kt++) {
                    bf16x8 bv0 = *(const bf16x8*)(w0lds + sp * 8192 + (kt * 2 + 0) * 1024 + l * 16);
                    bf16x8 bv1 = *(const bf16x8*)(w0lds + sp * 8192 + (kt * 2 + 1) * 1024 + l * 16);
                    acc0 = __builtin_amdgcn_mfma_f32_16x16x32_bf16(a[kt], bv0, acc0, 0, 0, 0);
                    acc1 = __builtin_amdgcn_mfma_f32_16x16x32_bf16(a[kt], bv1, acc1, 0, 0, 0);
                }
                // layer0 epilogue -> swizzled LDS (C layout -> A layout)
#pragma unroll
                for (int jt = 0; jt < 2; jt++) {
                    float bb = b0f[sp][jt];
#pragma unroll
                    for (int r = 0; r < 4; r++) {
                        float v = fast_tanh((jt ? acc1[r] : acc0[r]) + bb);
                        int roww = kg * 4 + r;
                        int col  = jt * 16 + lo;
                        int sw   = (col >> 3) ^ (roww & 3) ^ (roww >> 2);
                        h1buf[w][roww][sw * 8 + (col & 7)] = (__bf16)v;
                    }
                }
                int swr = kg ^ (lo & 3) ^ ((lo >> 2) & 3);
                bf16x8 ha = *(bf16x8*)&h1buf[w][lo][swr * 8];

                f32x4 c10 = {0.f, 0.f, 0.f, 0.f}, c11 = {0.f, 0.f, 0.f, 0.f};
                c10 = __builtin_amdgcn_mfma_f32_16x16x32_bf16(ha, w1f[sp][0], c10, 0, 0, 0);
                c11 = __builtin_amdgcn_mfma_f32_16x16x32_bf16(ha, w1f[sp][1], c11, 0, 0, 0);

#pragma unroll
                for (int r = 0; r < 4; r++) {
                    int spr = (r == 0) ? spr0 : (r == 1) ? spr1 : (r == 2) ? spr2 : spr3;
                    if (spr == sp) {
                        float h20 = fast_tanh(c10[r] + b1f[sp][0]);
                        float h21 = fast_tanh(c11[r] + b1f[sp][1]);
                        esum += h20 * w2f[sp][0] + h21 * w2f[sp][1];
                        if (lo == 0) esum += b2v[sp];   // once per row
                    }
                }
            }
        }
    }
#undef LOAD8

    // wave reduction + one atomic per wave
    esum += __shfl_xor(esum, 1);
    esum += __shfl_xor(esum, 2);
    esum += __shfl_xor(esum, 4);
    esum += __shfl_xor(esum, 8);
    esum += __shfl_xor(esum, 16);
    esum += __shfl_xor(esum, 32);
    if (l == 0) atomicAdd(out, esum);
}

extern "C" void kernel_launch(void* const* d_in, const int* in_sizes, int n_in,
                              void* d_out, int out_size, void* d_ws, size_t ws_size,
                              hipStream_t stream) {
    const float* desc    = (const float*)d_in[0];
    const int*   species = (const int*)d_in[1];
    const float* W0      = (const float*)d_in[2];
    const float* b0      = (const float*)d_in[3];
    const float* W1      = (const float*)d_in[4];
    const float* b1      = (const float*)d_in[5];
    const float* W2      = (const float*)d_in[6];
    const float* b2      = (const float*)d_in[7];
    char*  ws  = (char*)d_ws;
    float* out = (float*)d_out;

    kprep<<<1, 256, 0, stream>>>(W0, b0, W1, b1, W2, ws, out);
    k4_all<<<K4_BLOCKS, 256, 0, stream>>>(desc, species, b2, ws, out);
}